// Round 8
// baseline (536.167 us; speedup 1.0000x reference)
//
#include <hip/hip_runtime.h>

// ---------- types ----------
using bf16x8 = __attribute__((ext_vector_type(8))) short;           // 8 bf16 (4 VGPR)
using u16x8  = __attribute__((ext_vector_type(8))) unsigned short;  // 16B staging
using f32x4  = __attribute__((ext_vector_type(4))) float;
using f32x4v = __attribute__((ext_vector_type(4))) float;

__device__ inline unsigned short f2bf(float f) {
  unsigned int u = __builtin_bit_cast(unsigned int, f);
  return (unsigned short)((u + 0x7fffu + ((u >> 16) & 1u)) >> 16);  // RNE
}

#define MFMA16(a, b, c) __builtin_amdgcn_mfma_f32_16x16x32_bf16((a), (b), (c), 0, 0, 0)

// LDS-visibility-only barrier: drains lgkmcnt but NOT vmcnt, so register-
// destined global prefetches stay in flight across the sync (v3-proven).
__device__ __forceinline__ void lds_barrier() {
  __builtin_amdgcn_sched_barrier(0);
  asm volatile("s_waitcnt lgkmcnt(0)" ::: "memory");
  __builtin_amdgcn_sched_barrier(0);
  __builtin_amdgcn_s_barrier();
  __builtin_amdgcn_sched_barrier(0);
}

// Problem constants
#define LL 4096
#define NB 4
#define DD 512
#define KDIM 128

// ==========================================================================
// proj_qk (merged q+k): Out[b][l][128] = bf16( l2norm( X[l][b][:] @ Wk^T + bk ) )
// ==========================================================================
__global__ __launch_bounds__(256) void proj_qk_kernel(
    const float* __restrict__ Xq, const float* __restrict__ Xk,
    const float* __restrict__ Wk, const float* __restrict__ bk,
    unsigned short* __restrict__ Outq, unsigned short* __restrict__ Outk)
{
  __shared__ char smem[49152];                       // Xs 16KB | Ws 32KB
  char* Xs = smem;
  char* Ws = smem + 16384;

  const int tid = threadIdx.x;
  const int w = tid >> 6, lane = tid & 63, lr = lane & 15, g = lane >> 4;
  const int sel = blockIdx.x & 1;
  const float* X = sel ? Xk : Xq;
  unsigned short* Out = sel ? Outk : Outq;
  const int r0 = (blockIdx.x >> 1) * 64;

  f32x4 acc[8];
  #pragma unroll
  for (int nt = 0; nt < 8; ++nt) acc[nt] = f32x4{0.f, 0.f, 0.f, 0.f};

  for (int kc = 0; kc < 4; ++kc) {                   // K chunks of 128
    if (kc) __syncthreads();
    #pragma unroll
    for (int p = 0; p < 4; ++p) {
      int j = tid + p * 256;
      int row = j >> 4, e0 = (j & 15) * 8;
      const float* src = X + (size_t)(r0 + row) * DD + kc * 128 + e0;
      f32x4v f0 = *reinterpret_cast<const f32x4v*>(src);
      f32x4v f1 = *reinterpret_cast<const f32x4v*>(src + 4);
      u16x8 v;
      #pragma unroll
      for (int e = 0; e < 4; ++e) { v[e] = f2bf(f0[e]); v[e + 4] = f2bf(f1[e]); }
      *reinterpret_cast<u16x8*>(Xs + row * 256 + ((e0 * 2) ^ ((row & 7) << 4))) = v;
    }
    #pragma unroll
    for (int p = 0; p < 8; ++p) {
      int j = tid + p * 256;
      int n = j >> 4, e0 = (j & 15) * 8;
      const float* src = Wk + (size_t)n * DD + kc * 128 + e0;
      f32x4v f0 = *reinterpret_cast<const f32x4v*>(src);
      f32x4v f1 = *reinterpret_cast<const f32x4v*>(src + 4);
      u16x8 v;
      #pragma unroll
      for (int e = 0; e < 4; ++e) { v[e] = f2bf(f0[e]); v[e + 4] = f2bf(f1[e]); }
      *reinterpret_cast<u16x8*>(Ws + n * 256 + ((e0 * 2) ^ ((n & 7) << 4))) = v;
    }
    __syncthreads();
    const int arow = w * 16 + lr;
    #pragma unroll
    for (int ks = 0; ks < 4; ++ks) {
      int oa = (ks * 64 + g * 16) ^ ((arow & 7) << 4);
      bf16x8 a = *reinterpret_cast<const bf16x8*>(Xs + arow * 256 + oa);
      #pragma unroll
      for (int nt = 0; nt < 8; ++nt) {
        int n = nt * 16 + lr;
        int ob = (ks * 64 + g * 16) ^ ((n & 7) << 4);
        bf16x8 bb = *reinterpret_cast<const bf16x8*>(Ws + n * 256 + ob);
        acc[nt] = MFMA16(a, bb, acc[nt]);
      }
    }
  }

  float bias[8];
  #pragma unroll
  for (int nt = 0; nt < 8; ++nt) bias[nt] = bk[nt * 16 + lr];
  #pragma unroll
  for (int nt = 0; nt < 8; ++nt)
    #pragma unroll
    for (int i = 0; i < 4; ++i) acc[nt][i] += bias[nt];

  f32x4 ss = f32x4{0.f, 0.f, 0.f, 0.f};
  #pragma unroll
  for (int nt = 0; nt < 8; ++nt)
    #pragma unroll
    for (int i = 0; i < 4; ++i) ss[i] += acc[nt][i] * acc[nt][i];
  #pragma unroll
  for (int m = 1; m < 16; m <<= 1) {
    #pragma unroll
    for (int i = 0; i < 4; ++i) ss[i] += __shfl_xor(ss[i], m);
  }
  float inv[4];
  #pragma unroll
  for (int i = 0; i < 4; ++i) inv[i] = 1.0f / fmaxf(sqrtf(ss[i]), 1e-12f);

  #pragma unroll
  for (int nt = 0; nt < 8; ++nt) {
    int c = nt * 16 + lr;
    #pragma unroll
    for (int i = 0; i < 4; ++i) {
      int r = r0 + w * 16 + g * 4 + i;
      int l = r >> 2, b = r & 3;
      Out[((size_t)(b * LL + l)) * KDIM + c] = f2bf(acc[nt][i] * inv[i]);
    }
  }
}

// ==========================================================================
// proj_v: Vt[b][d][s] = bf16( value[s][b][:] @ Wv^T + bv )   (transposed store)
// ==========================================================================
__global__ __launch_bounds__(256) void proj_v_kernel(
    const float* __restrict__ X, const float* __restrict__ Wv,
    const float* __restrict__ bv, unsigned short* __restrict__ VtOut)
{
  __shared__ char smem[40960];
  char* Xs = smem;
  char* Ws = smem + 32768;

  const int tid = threadIdx.x;
  const int w = tid >> 6, lane = tid & 63, lr = lane & 15, g = lane >> 4;
  const int rb = blockIdx.x >> 3, nb = blockIdx.x & 7;
  const int r0 = rb * 256, d0 = nb * 64;

  f32x4 acc[4][4];
  #pragma unroll
  for (int rt = 0; rt < 4; ++rt)
    #pragma unroll
    for (int nt = 0; nt < 4; ++nt) acc[rt][nt] = f32x4{0.f, 0.f, 0.f, 0.f};

  for (int kc = 0; kc < 8; ++kc) {
    if (kc) __syncthreads();
    #pragma unroll
    for (int p = 0; p < 8; ++p) {
      int j = tid + p * 256;
      int row = j >> 3, e0 = (j & 7) * 8;
      const float* src = X + (size_t)(r0 + row) * DD + kc * 64 + e0;
      f32x4v f0 = *reinterpret_cast<const f32x4v*>(src);
      f32x4v f1 = *reinterpret_cast<const f32x4v*>(src + 4);
      u16x8 v;
      #pragma unroll
      for (int e = 0; e < 4; ++e) { v[e] = f2bf(f0[e]); v[e + 4] = f2bf(f1[e]); }
      *reinterpret_cast<u16x8*>(Xs + row * 128 + ((e0 * 2) ^ ((row & 7) << 4))) = v;
    }
    #pragma unroll
    for (int p = 0; p < 2; ++p) {
      int j = tid + p * 256;
      int n = j >> 3, e0 = (j & 7) * 8;
      const float* src = Wv + (size_t)(d0 + n) * DD + kc * 64 + e0;
      f32x4v f0 = *reinterpret_cast<const f32x4v*>(src);
      f32x4v f1 = *reinterpret_cast<const f32x4v*>(src + 4);
      u16x8 v;
      #pragma unroll
      for (int e = 0; e < 4; ++e) { v[e] = f2bf(f0[e]); v[e + 4] = f2bf(f1[e]); }
      *reinterpret_cast<u16x8*>(Ws + n * 128 + ((e0 * 2) ^ ((n & 7) << 4))) = v;
    }
    __syncthreads();
    #pragma unroll
    for (int ks = 0; ks < 2; ++ks) {
      bf16x8 a[4];
      #pragma unroll
      for (int rt = 0; rt < 4; ++rt) {
        int arow = w * 64 + rt * 16 + lr;
        a[rt] = *reinterpret_cast<const bf16x8*>(
            Xs + arow * 128 + ((ks * 64 + g * 16) ^ ((arow & 7) << 4)));
      }
      #pragma unroll
      for (int nt = 0; nt < 4; ++nt) {
        int n = nt * 16 + lr;
        bf16x8 bb = *reinterpret_cast<const bf16x8*>(
            Ws + n * 128 + ((ks * 64 + g * 16) ^ ((n & 7) << 4)));
        #pragma unroll
        for (int rt = 0; rt < 4; ++rt) acc[rt][nt] = MFMA16(a[rt], bb, acc[rt][nt]);
      }
    }
  }

  __syncthreads();
  float bias[4];
  #pragma unroll
  for (int nt = 0; nt < 4; ++nt) bias[nt] = bv[d0 + nt * 16 + lr];

  unsigned short* Ts = (unsigned short*)smem;
  #pragma unroll
  for (int rt = 0; rt < 4; ++rt)
    #pragma unroll
    for (int nt = 0; nt < 4; ++nt) {
      int dl = nt * 16 + lr;
      #pragma unroll
      for (int i = 0; i < 4; ++i) {
        int rl = w * 64 + rt * 16 + g * 4 + i;
        Ts[dl * 256 + (rl ^ ((dl & 31) << 1))] = f2bf(acc[rt][nt][i] + bias[nt]);
      }
    }
  __syncthreads();

  int bsel = tid >> 6, dl = tid & 63;
  int l0 = r0 >> 2;
  #pragma unroll
  for (int jj = 0; jj < 8; ++jj) {
    u16x8 v;
    #pragma unroll
    for (int e = 0; e < 8; ++e) {
      int rl = (jj * 8 + e) * 4 + bsel;
      v[e] = Ts[dl * 256 + (rl ^ ((dl & 31) << 1))];
    }
    *reinterpret_cast<u16x8*>(VtOut + ((size_t)(bsel * DD + d0 + dl)) * LL + l0 + jj * 8) = v;
  }
}

// ==========================================================================
// attn v8: producer/consumer wave specialization. Block 512 thr / 8 waves,
// grid 256 (1 block/CU, 2 waves/SIMD: one S-wave + one PV-wave per SIMD).
//   S-waves (w=0..3): S(t) = Q(16q x 128k) x K(t)^T -> exp -> P(t) LDS write.
//   PV-waves (w=4..7): PV(t-1) = P(t-1)(64q) x V(t-1)(64s x 128d-slice),
//     V in regs (consume-then-refill, 1-period cover), pure-MFMA profile.
// The SIMD co-schedules the LDS/VALU-heavy producer under the consumer's
// 64-MFMA shadow -> pipes overlap instead of convoying.
// K tile dbuf + P tile dbuf in LDS; one lgkm-only barrier per step.
// ==========================================================================
#define KBLK 64
#define NIT (LL / KBLK)          // 64 steps

__global__ __launch_bounds__(512, 2) void attn_kernel(
    const unsigned short* __restrict__ Qn, const unsigned short* __restrict__ Kn,
    const unsigned short* __restrict__ Vt, float* __restrict__ Out)
{
  __shared__ char smem[49408];
  char* Ks0 = smem;                                  // [64 s][128 k] bf16, 16KB
  char* Ks1 = smem + 16384;
  char* Ps0 = smem + 32768;                          // [64 q][64 s] bf16, 8KB
  char* Ps1 = smem + 40960;
  float* Ls = (float*)(smem + 49152);                // [64] row sums

  const int tid = threadIdx.x;
  const int w = tid >> 6, lane = tid & 63, lr = lane & 15, g = lane >> 4;
  const bool isS = (w < 4);
  const int wi = w & 3;                              // S: q-subtile; PV: d-slice
  const int r0k = tid >> 4, c0k = (tid & 15) * 8;    // K staging mapping

  // XCD-grouping swizzle: batch b -> XCD pair {2b,2b+1} (rr dispatch)
  const int bid = blockIdx.x;
  const int b = (bid & 7) >> 1;
  const int tile = ((bid >> 3) << 1) | (bid & 1);
  const int q0 = tile * 64;

  const unsigned short* Kp = Kn + (size_t)b * LL * KDIM;
  const unsigned short* Vp = Vt + ((size_t)b * DD + wi * 128) * LL;  // PV base

  // S-wave state: Q A-fragments (16 q rows x 128 k)
  bf16x8 qf[4];
  if (isS) {
    const unsigned short* qp =
        Qn + ((size_t)(b * LL + q0 + wi * 16 + lr)) * KDIM + g * 8;
    #pragma unroll
    for (int kc = 0; kc < 4; ++kc)
      qf[kc] = *reinterpret_cast<const bf16x8*>(qp + kc * 32);
  }
  float lsum[4] = {0.f, 0.f, 0.f, 0.f};

  // PV-wave state: acc 64q x 128d-slice, V frags (16 x 16B)
  f32x4 acc[4][8];
  #pragma unroll
  for (int qt = 0; qt < 4; ++qt)
    #pragma unroll
    for (int dt = 0; dt < 8; ++dt) acc[qt][dt] = f32x4{0.f, 0.f, 0.f, 0.f};
  bf16x8 vf[8][2];

  // ---- prologue: K(0) -> Ks0 ----
  {
    u16x8 k0 = *reinterpret_cast<const u16x8*>(Kp + (size_t)r0k * KDIM + c0k);
    u16x8 k1 = *reinterpret_cast<const u16x8*>(Kp + (size_t)(r0k + 32) * KDIM + c0k);
    int sw = (r0k & 7) << 4;
    *reinterpret_cast<u16x8*>(Ks0 + r0k * 256 + ((c0k * 2) ^ sw)) = k0;
    *reinterpret_cast<u16x8*>(Ks0 + (r0k + 32) * 256 + ((c0k * 2) ^ sw)) = k1;
  }
  __syncthreads();

  for (int t = 0; t < NIT; ++t) {
    const char* kcur = (t & 1) ? Ks1 : Ks0;
    char* knxt = (t & 1) ? Ks0 : Ks1;
    const char* prd = (t & 1) ? Ps0 : Ps1;           // P(t-1)
    char* pwr = (t & 1) ? Ps1 : Ps0;                 // P(t)
    const int tn = (t < NIT - 1) ? t + 1 : t;

    // ---- issue K(t+1) -> regs (oldest vmcnt; spans the barrier window) ----
    u16x8 k0 = *reinterpret_cast<const u16x8*>(
        Kp + ((size_t)(tn * KBLK + r0k)) * KDIM + c0k);
    u16x8 k1 = *reinterpret_cast<const u16x8*>(
        Kp + ((size_t)(tn * KBLK + r0k + 32)) * KDIM + c0k);

    if (isS) {
      // ================= producer: S(t) -> P(t) =================
      bf16x8 kb[4][4];
      #pragma unroll
      for (int st = 0; st < 4; ++st) {
        int s = st * 16 + lr, sw = (s & 7) << 4;
        #pragma unroll
        for (int kc = 0; kc < 4; ++kc)
          kb[st][kc] = *reinterpret_cast<const bf16x8*>(
              kcur + s * 256 + ((kc * 64 + g * 16) ^ sw));
      }
      __builtin_amdgcn_sched_barrier(0);
      asm volatile("s_waitcnt lgkmcnt(0)" ::: "memory");
      __builtin_amdgcn_sched_barrier(0);
      f32x4 sacc[4];
      #pragma unroll
      for (int st = 0; st < 4; ++st) sacc[st] = f32x4{0.f, 0.f, 0.f, 0.f};
      #pragma unroll
      for (int st = 0; st < 4; ++st)
        #pragma unroll
        for (int kc = 0; kc < 4; ++kc)
          sacc[st] = MFMA16(qf[kc], kb[st][kc], sacc[st]);
      #pragma unroll
      for (int st = 0; st < 4; ++st)
        #pragma unroll
        for (int i = 0; i < 4; ++i) {
          float p = exp2f(fmaf(sacc[st][i], 43.280851f, -44.723546f));
          lsum[i] += p;
          int q = wi * 16 + g * 4 + i;
          int s = st * 16 + lr;
          *(unsigned short*)(pwr + q * 128 + ((s * 2) ^ ((q & 7) << 4))) = f2bf(p);
        }
    } else {
      // ================= consumer: PV(t-1) =================
      if (t) {
        bf16x8 pa[4][2];
        #pragma unroll
        for (int qt = 0; qt < 4; ++qt) {
          int q = qt * 16 + lr, sw = (q & 7) << 4;
          pa[qt][0] = *reinterpret_cast<const bf16x8*>(prd + q * 128 + ((g * 16) ^ sw));
          pa[qt][1] = *reinterpret_cast<const bf16x8*>(prd + q * 128 + ((64 + g * 16) ^ sw));
        }
        __builtin_amdgcn_sched_barrier(0);
        asm volatile("s_waitcnt lgkmcnt(0)" ::: "memory");
        __builtin_amdgcn_sched_barrier(0);
        __builtin_amdgcn_s_setprio(1);
        #pragma unroll
        for (int qt = 0; qt < 4; ++qt)
          #pragma unroll
          for (int dt = 0; dt < 8; ++dt) {
            acc[qt][dt] = MFMA16(pa[qt][0], vf[dt][0], acc[qt][dt]);
            acc[qt][dt] = MFMA16(pa[qt][1], vf[dt][1], acc[qt][dt]);
          }
        __builtin_amdgcn_s_setprio(0);
      }
      // issue V(t) into the just-consumed regs (1-period cover)
      #pragma unroll
      for (int dt = 0; dt < 8; ++dt)
        #pragma unroll
        for (int sc = 0; sc < 2; ++sc)
          vf[dt][sc] = *reinterpret_cast<const bf16x8*>(
              Vp + (size_t)(dt * 16 + lr) * LL + t * KBLK + sc * 32 + g * 8);
    }

    // ---- write staged K(t+1) -> other buffer (counted vmcnt) ----
    {
      int sw = (r0k & 7) << 4;
      *reinterpret_cast<u16x8*>(knxt + r0k * 256 + ((c0k * 2) ^ sw)) = k0;
      *reinterpret_cast<u16x8*>(knxt + (r0k + 32) * 256 + ((c0k * 2) ^ sw)) = k1;
    }
    lds_barrier();   // lgkm-only: V/K global loads stay in flight
  }

  // ---- S-waves publish row sums (each owns full s-range for its rows) ----
  if (isS) {
    #pragma unroll
    for (int m = 1; m < 16; m <<= 1) {
      #pragma unroll
      for (int i = 0; i < 4; ++i) lsum[i] += __shfl_xor(lsum[i], m);
    }
    if (lr == 0) {
      #pragma unroll
      for (int i = 0; i < 4; ++i) Ls[wi * 16 + g * 4 + i] = lsum[i];
    }
  }
  __syncthreads();

  // ---- PV-waves: final PV(63) + scale + store ----
  if (!isS) {
    bf16x8 pa[4][2];
    #pragma unroll
    for (int qt = 0; qt < 4; ++qt) {
      int q = qt * 16 + lr, sw = (q & 7) << 4;
      pa[qt][0] = *reinterpret_cast<const bf16x8*>(Ps1 + q * 128 + ((g * 16) ^ sw));
      pa[qt][1] = *reinterpret_cast<const bf16x8*>(Ps1 + q * 128 + ((64 + g * 16) ^ sw));
    }
    #pragma unroll
    for (int qt = 0; qt < 4; ++qt)
      #pragma unroll
      for (int dt = 0; dt < 8; ++dt) {
        acc[qt][dt] = MFMA16(pa[qt][0], vf[dt][0], acc[qt][dt]);
        acc[qt][dt] = MFMA16(pa[qt][1], vf[dt][1], acc[qt][dt]);
      }
    #pragma unroll
    for (int qt = 0; qt < 4; ++qt) {
      #pragma unroll
      for (int i = 0; i < 4; ++i) {
        int ql = qt * 16 + g * 4 + i;
        float linv = 1.0f / Ls[ql];
        size_t o = ((size_t)(q0 + ql) * NB + b) * DD + wi * 128 + lr;
        #pragma unroll
        for (int dt = 0; dt < 8; ++dt)
          Out[o + dt * 16] = acc[qt][dt][i] * linv;
      }
    }
  }
}

// ==========================================================================
extern "C" void kernel_launch(void* const* d_in, const int* in_sizes, int n_in,
                              void* d_out, int out_size, void* d_ws, size_t ws_size,
                              hipStream_t stream) {
  const float* query = (const float*)d_in[0];
  const float* key   = (const float*)d_in[1];
  const float* value = (const float*)d_in[2];
  const float* WKw   = (const float*)d_in[3];
  const float* WKb   = (const float*)d_in[4];
  const float* WVw   = (const float*)d_in[5];
  const float* WVb   = (const float*)d_in[6];
  float* out = (float*)d_out;

  unsigned short* wqn = (unsigned short*)d_ws;            // [4][4096][128] bf16
  unsigned short* wkn = wqn + (size_t)NB * LL * KDIM;     // [4][4096][128] bf16
  unsigned short* vt  = wkn + (size_t)NB * LL * KDIM;     // [4][512][4096] bf16

  proj_qk_kernel<<<512, 256, 0, stream>>>(query, key, WKw, WKb, wqn, wkn);
  proj_v_kernel <<<512, 256, 0, stream>>>(value, WVw, WVb, vt);
  attn_kernel   <<<256, 512, 0, stream>>>(wqn, wkn, vt, out);
}

// Round 9
// 374.930 us; speedup vs baseline: 1.4300x; 1.4300x over previous
//
#include <hip/hip_runtime.h>

// ---------- types ----------
using bf16x8 = __attribute__((ext_vector_type(8))) short;           // 8 bf16 (4 VGPR)
using u16x8  = __attribute__((ext_vector_type(8))) unsigned short;  // 16B staging
using f32x4  = __attribute__((ext_vector_type(4))) float;
using f32x4v = __attribute__((ext_vector_type(4))) float;

__device__ inline unsigned short f2bf(float f) {
  unsigned int u = __builtin_bit_cast(unsigned int, f);
  return (unsigned short)((u + 0x7fffu + ((u >> 16) & 1u)) >> 16);  // RNE
}

#define MFMA16(a, b, c) __builtin_amdgcn_mfma_f32_16x16x32_bf16((a), (b), (c), 0, 0, 0)

// LDS-visibility-only barrier: drains lgkmcnt but NOT vmcnt, so register-
// destined global prefetches stay in flight across the sync (v3-proven).
__device__ __forceinline__ void lds_barrier() {
  __builtin_amdgcn_sched_barrier(0);
  asm volatile("s_waitcnt lgkmcnt(0)" ::: "memory");
  __builtin_amdgcn_sched_barrier(0);
  __builtin_amdgcn_s_barrier();
  __builtin_amdgcn_sched_barrier(0);
}

// Problem constants
#define LL 4096
#define NB 4
#define DD 512
#define KDIM 128

// ==========================================================================
// proj_qk (merged q+k): Out[b][l][128] = bf16( l2norm( X[l][b][:] @ Wk^T + bk ) )
// ==========================================================================
__global__ __launch_bounds__(256) void proj_qk_kernel(
    const float* __restrict__ Xq, const float* __restrict__ Xk,
    const float* __restrict__ Wk, const float* __restrict__ bk,
    unsigned short* __restrict__ Outq, unsigned short* __restrict__ Outk)
{
  __shared__ char smem[49152];                       // Xs 16KB | Ws 32KB
  char* Xs = smem;
  char* Ws = smem + 16384;

  const int tid = threadIdx.x;
  const int w = tid >> 6, lane = tid & 63, lr = lane & 15, g = lane >> 4;
  const int sel = blockIdx.x & 1;
  const float* X = sel ? Xk : Xq;
  unsigned short* Out = sel ? Outk : Outq;
  const int r0 = (blockIdx.x >> 1) * 64;

  f32x4 acc[8];
  #pragma unroll
  for (int nt = 0; nt < 8; ++nt) acc[nt] = f32x4{0.f, 0.f, 0.f, 0.f};

  for (int kc = 0; kc < 4; ++kc) {                   // K chunks of 128
    if (kc) __syncthreads();
    #pragma unroll
    for (int p = 0; p < 4; ++p) {
      int j = tid + p * 256;
      int row = j >> 4, e0 = (j & 15) * 8;
      const float* src = X + (size_t)(r0 + row) * DD + kc * 128 + e0;
      f32x4v f0 = *reinterpret_cast<const f32x4v*>(src);
      f32x4v f1 = *reinterpret_cast<const f32x4v*>(src + 4);
      u16x8 v;
      #pragma unroll
      for (int e = 0; e < 4; ++e) { v[e] = f2bf(f0[e]); v[e + 4] = f2bf(f1[e]); }
      *reinterpret_cast<u16x8*>(Xs + row * 256 + ((e0 * 2) ^ ((row & 7) << 4))) = v;
    }
    #pragma unroll
    for (int p = 0; p < 8; ++p) {
      int j = tid + p * 256;
      int n = j >> 4, e0 = (j & 15) * 8;
      const float* src = Wk + (size_t)n * DD + kc * 128 + e0;
      f32x4v f0 = *reinterpret_cast<const f32x4v*>(src);
      f32x4v f1 = *reinterpret_cast<const f32x4v*>(src + 4);
      u16x8 v;
      #pragma unroll
      for (int e = 0; e < 4; ++e) { v[e] = f2bf(f0[e]); v[e + 4] = f2bf(f1[e]); }
      *reinterpret_cast<u16x8*>(Ws + n * 256 + ((e0 * 2) ^ ((n & 7) << 4))) = v;
    }
    __syncthreads();
    const int arow = w * 16 + lr;
    #pragma unroll
    for (int ks = 0; ks < 4; ++ks) {
      int oa = (ks * 64 + g * 16) ^ ((arow & 7) << 4);
      bf16x8 a = *reinterpret_cast<const bf16x8*>(Xs + arow * 256 + oa);
      #pragma unroll
      for (int nt = 0; nt < 8; ++nt) {
        int n = nt * 16 + lr;
        int ob = (ks * 64 + g * 16) ^ ((n & 7) << 4);
        bf16x8 bb = *reinterpret_cast<const bf16x8*>(Ws + n * 256 + ob);
        acc[nt] = MFMA16(a, bb, acc[nt]);
      }
    }
  }

  float bias[8];
  #pragma unroll
  for (int nt = 0; nt < 8; ++nt) bias[nt] = bk[nt * 16 + lr];
  #pragma unroll
  for (int nt = 0; nt < 8; ++nt)
    #pragma unroll
    for (int i = 0; i < 4; ++i) acc[nt][i] += bias[nt];

  f32x4 ss = f32x4{0.f, 0.f, 0.f, 0.f};
  #pragma unroll
  for (int nt = 0; nt < 8; ++nt)
    #pragma unroll
    for (int i = 0; i < 4; ++i) ss[i] += acc[nt][i] * acc[nt][i];
  #pragma unroll
  for (int m = 1; m < 16; m <<= 1) {
    #pragma unroll
    for (int i = 0; i < 4; ++i) ss[i] += __shfl_xor(ss[i], m);
  }
  float inv[4];
  #pragma unroll
  for (int i = 0; i < 4; ++i) inv[i] = 1.0f / fmaxf(sqrtf(ss[i]), 1e-12f);

  #pragma unroll
  for (int nt = 0; nt < 8; ++nt) {
    int c = nt * 16 + lr;
    #pragma unroll
    for (int i = 0; i < 4; ++i) {
      int r = r0 + w * 16 + g * 4 + i;
      int l = r >> 2, b = r & 3;
      Out[((size_t)(b * LL + l)) * KDIM + c] = f2bf(acc[nt][i] * inv[i]);
    }
  }
}

// ==========================================================================
// proj_v: Vt[b][d][s] = bf16( value[s][b][:] @ Wv^T + bv )   (transposed store)
// ==========================================================================
__global__ __launch_bounds__(256) void proj_v_kernel(
    const float* __restrict__ X, const float* __restrict__ Wv,
    const float* __restrict__ bv, unsigned short* __restrict__ VtOut)
{
  __shared__ char smem[40960];
  char* Xs = smem;
  char* Ws = smem + 32768;

  const int tid = threadIdx.x;
  const int w = tid >> 6, lane = tid & 63, lr = lane & 15, g = lane >> 4;
  const int rb = blockIdx.x >> 3, nb = blockIdx.x & 7;
  const int r0 = rb * 256, d0 = nb * 64;

  f32x4 acc[4][4];
  #pragma unroll
  for (int rt = 0; rt < 4; ++rt)
    #pragma unroll
    for (int nt = 0; nt < 4; ++nt) acc[rt][nt] = f32x4{0.f, 0.f, 0.f, 0.f};

  for (int kc = 0; kc < 8; ++kc) {
    if (kc) __syncthreads();
    #pragma unroll
    for (int p = 0; p < 8; ++p) {
      int j = tid + p * 256;
      int row = j >> 3, e0 = (j & 7) * 8;
      const float* src = X + (size_t)(r0 + row) * DD + kc * 64 + e0;
      f32x4v f0 = *reinterpret_cast<const f32x4v*>(src);
      f32x4v f1 = *reinterpret_cast<const f32x4v*>(src + 4);
      u16x8 v;
      #pragma unroll
      for (int e = 0; e < 4; ++e) { v[e] = f2bf(f0[e]); v[e + 4] = f2bf(f1[e]); }
      *reinterpret_cast<u16x8*>(Xs + row * 128 + ((e0 * 2) ^ ((row & 7) << 4))) = v;
    }
    #pragma unroll
    for (int p = 0; p < 2; ++p) {
      int j = tid + p * 256;
      int n = j >> 3, e0 = (j & 7) * 8;
      const float* src = Wv + (size_t)(d0 + n) * DD + kc * 64 + e0;
      f32x4v f0 = *reinterpret_cast<const f32x4v*>(src);
      f32x4v f1 = *reinterpret_cast<const f32x4v*>(src + 4);
      u16x8 v;
      #pragma unroll
      for (int e = 0; e < 4; ++e) { v[e] = f2bf(f0[e]); v[e + 4] = f2bf(f1[e]); }
      *reinterpret_cast<u16x8*>(Ws + n * 128 + ((e0 * 2) ^ ((n & 7) << 4))) = v;
    }
    __syncthreads();
    #pragma unroll
    for (int ks = 0; ks < 2; ++ks) {
      bf16x8 a[4];
      #pragma unroll
      for (int rt = 0; rt < 4; ++rt) {
        int arow = w * 64 + rt * 16 + lr;
        a[rt] = *reinterpret_cast<const bf16x8*>(
            Xs + arow * 128 + ((ks * 64 + g * 16) ^ ((arow & 7) << 4)));
      }
      #pragma unroll
      for (int nt = 0; nt < 4; ++nt) {
        int n = nt * 16 + lr;
        bf16x8 bb = *reinterpret_cast<const bf16x8*>(
            Ws + n * 128 + ((ks * 64 + g * 16) ^ ((n & 7) << 4)));
        #pragma unroll
        for (int rt = 0; rt < 4; ++rt) acc[rt][nt] = MFMA16(a[rt], bb, acc[rt][nt]);
      }
    }
  }

  __syncthreads();
  float bias[4];
  #pragma unroll
  for (int nt = 0; nt < 4; ++nt) bias[nt] = bv[d0 + nt * 16 + lr];

  unsigned short* Ts = (unsigned short*)smem;
  #pragma unroll
  for (int rt = 0; rt < 4; ++rt)
    #pragma unroll
    for (int nt = 0; nt < 4; ++nt) {
      int dl = nt * 16 + lr;
      #pragma unroll
      for (int i = 0; i < 4; ++i) {
        int rl = w * 64 + rt * 16 + g * 4 + i;
        Ts[dl * 256 + (rl ^ ((dl & 31) << 1))] = f2bf(acc[rt][nt][i] + bias[nt]);
      }
    }
  __syncthreads();

  int bsel = tid >> 6, dl = tid & 63;
  int l0 = r0 >> 2;
  #pragma unroll
  for (int jj = 0; jj < 8; ++jj) {
    u16x8 v;
    #pragma unroll
    for (int e = 0; e < 8; ++e) {
      int rl = (jj * 8 + e) * 4 + bsel;
      v[e] = Ts[dl * 256 + (rl ^ ((dl & 31) << 1))];
    }
    *reinterpret_cast<u16x8*>(VtOut + ((size_t)(bsel * DD + d0 + dl)) * LL + l0 + jj * 8) = v;
  }
}

// ==========================================================================
// attn v9: v3's proven dataflow, halved tile (QBLK=32) -> grid 512 ->
// TWO independent barrier domains per CU (4 waves/SIMD total). Register
// demand trimmed to fit the 128-VGPR cap cleanly: acc[2][4]=32, V single-
// buffered (consume-then-refill), qf=16, kst=8.
// Block 512 thr / 8 waves. Wave w = (wq=w&1, ws=w>>1):
//   S: q[wq*16,+16) x s[ws*16,+16); PV: all 32 q x d-slice [w*64,+64).
// K tile [64][128] dbuf + P tile [32][64] dbuf in LDS (40KB -> 2 blocks/CU).
// One lgkm-only barrier per step; K/V global prefetches span it.
// ==========================================================================
#define QBLK 32
#define KBLK 64
#define NIT (LL / KBLK)          // 64 steps

__global__ __launch_bounds__(512, 4) void attn_kernel(
    const unsigned short* __restrict__ Qn, const unsigned short* __restrict__ Kn,
    const unsigned short* __restrict__ Vt, float* __restrict__ Out)
{
  __shared__ char smem[41472];
  char* Ks0 = smem;                                  // [64 s][128 k] bf16, 16KB
  char* Ks1 = smem + 16384;
  char* Ps0 = smem + 32768;                          // [32 q][64 s] bf16, 4KB
  char* Ps1 = smem + 36864;
  float* Ls = (float*)(smem + 40960);                // [4 ws][32 q] partial sums

  const int tid = threadIdx.x;
  const int w = tid >> 6, lane = tid & 63, lr = lane & 15, g = lane >> 4;
  const int wq = w & 1, ws = w >> 1;
  const int r0k = tid >> 4, c0k = (tid & 15) * 8;    // K staging mapping

  // XCD-grouping swizzle: co-XCD blocks share a batch (bid&7 fixed per XCD)
  const int bid = blockIdx.x;
  const int b = (bid & 7) >> 1;
  const int tile = ((bid >> 3) << 1) | (bid & 1);    // 0..127
  const int q0 = tile * QBLK;

  const unsigned short* Kp = Kn + (size_t)b * LL * KDIM;
  const unsigned short* Vp = Vt + (size_t)b * DD * LL;

  // Q A-fragments (16 q rows x 128 k)
  bf16x8 qf[4];
  {
    const unsigned short* qp =
        Qn + ((size_t)(b * LL + q0 + wq * 16 + lr)) * KDIM + g * 8;
    #pragma unroll
    for (int kc = 0; kc < 4; ++kc)
      qf[kc] = *reinterpret_cast<const bf16x8*>(qp + kc * 32);
  }

  f32x4 acc[2][4];
  #pragma unroll
  for (int qt = 0; qt < 2; ++qt)
    #pragma unroll
    for (int ch = 0; ch < 4; ++ch) acc[qt][ch] = f32x4{0.f, 0.f, 0.f, 0.f};
  float lsum[4] = {0.f, 0.f, 0.f, 0.f};

  bf16x8 vf[4][2];                                   // single V set (32 VGPR)

  // ---- prologue: K(0) -> Ks0, V(0) -> vf ----
  {
    u16x8 k0 = *reinterpret_cast<const u16x8*>(Kp + (size_t)r0k * KDIM + c0k);
    u16x8 k1 = *reinterpret_cast<const u16x8*>(Kp + (size_t)(r0k + 32) * KDIM + c0k);
    int sw = (r0k & 7) << 4;
    *reinterpret_cast<u16x8*>(Ks0 + r0k * 256 + ((c0k * 2) ^ sw)) = k0;
    *reinterpret_cast<u16x8*>(Ks0 + (r0k + 32) * 256 + ((c0k * 2) ^ sw)) = k1;
    #pragma unroll
    for (int ch = 0; ch < 4; ++ch)
      #pragma unroll
      for (int sc = 0; sc < 2; ++sc)
        vf[ch][sc] = *reinterpret_cast<const bf16x8*>(
            Vp + (size_t)(w * 64 + ch * 16 + lr) * LL + sc * 32 + g * 8);
  }
  __syncthreads();

  for (int t = 0; t < NIT; ++t) {
    const char* kcur = (t & 1) ? Ks1 : Ks0;
    char* knxt = (t & 1) ? Ks0 : Ks1;
    char* pcur = (t & 1) ? Ps1 : Ps0;                // P(t): written & read this step
    const int tn = (t < NIT - 1) ? t + 1 : t;

    // ---- issue K(t+1) -> regs (oldest vmcnt; spans the barrier) ----
    u16x8 k0 = *reinterpret_cast<const u16x8*>(
        Kp + ((size_t)(tn * KBLK + r0k)) * KDIM + c0k);
    u16x8 k1 = *reinterpret_cast<const u16x8*>(
        Kp + ((size_t)(tn * KBLK + r0k + 32)) * KDIM + c0k);

    // ---- S phase: 16 q x 16 s from Ks[cur] ----
    f32x4 s0 = f32x4{0.f, 0.f, 0.f, 0.f};
    const int sr = ws * 16 + lr;
    #pragma unroll
    for (int kc = 0; kc < 4; ++kc) {
      bf16x8 kb = *reinterpret_cast<const bf16x8*>(
          kcur + sr * 256 + ((kc * 64 + g * 16) ^ ((sr & 7) << 4)));
      s0 = MFMA16(qf[kc], kb, s0);
    }

    // ---- softmax numerator (fixed max 31) + P(t) write ----
    #pragma unroll
    for (int i = 0; i < 4; ++i) {
      float p = exp2f(fmaf(s0[i], 43.280851f, -44.723546f));
      lsum[i] += p;
      int q = wq * 16 + g * 4 + i;
      *(unsigned short*)(pcur + q * 128 + ((sr * 2) ^ ((q & 7) << 4))) = f2bf(p);
    }

    // ---- write staged K(t+1) -> other buffer (counted vmcnt) ----
    {
      int sw = (r0k & 7) << 4;
      *reinterpret_cast<u16x8*>(knxt + r0k * 256 + ((c0k * 2) ^ sw)) = k0;
      *reinterpret_cast<u16x8*>(knxt + (r0k + 32) * 256 + ((c0k * 2) ^ sw)) = k1;
    }

    lds_barrier();   // lgkm-only: V/K global loads stay in flight

    // ---- PV phase: all 32 q x this wave's 64-wide d slice ----
    #pragma unroll
    for (int qt = 0; qt < 2; ++qt) {
      int q = qt * 16 + lr;
      int sw = (q & 7) << 4;
      bf16x8 pa0 = *reinterpret_cast<const bf16x8*>(pcur + q * 128 + ((g * 16) ^ sw));
      bf16x8 pa1 = *reinterpret_cast<const bf16x8*>(pcur + q * 128 + ((64 + g * 16) ^ sw));
      #pragma unroll
      for (int ch = 0; ch < 4; ++ch) {
        acc[qt][ch] = MFMA16(pa0, vf[ch][0], acc[qt][ch]);
        acc[qt][ch] = MFMA16(pa1, vf[ch][1], acc[qt][ch]);
      }
    }

    // ---- refill vf with V(t+1) (WAR-ordered after PV; ~1 step of cover) ----
    #pragma unroll
    for (int ch = 0; ch < 4; ++ch)
      #pragma unroll
      for (int sc = 0; sc < 2; ++sc)
        vf[ch][sc] = *reinterpret_cast<const bf16x8*>(
            Vp + (size_t)(w * 64 + ch * 16 + lr) * LL + tn * KBLK + sc * 32 + g * 8);
  }

  // ---- combine partial row sums across the four s-slices ----
  #pragma unroll
  for (int m = 1; m < 16; m <<= 1) {
    #pragma unroll
    for (int i = 0; i < 4; ++i) lsum[i] += __shfl_xor(lsum[i], m);
  }
  if (lr == 0) {
    #pragma unroll
    for (int i = 0; i < 4; ++i)
      Ls[ws * 32 + wq * 16 + g * 4 + i] = lsum[i];
  }
  __syncthreads();

  // ---- scale by 1/l and store ----
  #pragma unroll
  for (int qt = 0; qt < 2; ++qt) {
    float linv[4];
    #pragma unroll
    for (int i = 0; i < 4; ++i) {
      int ql = qt * 16 + g * 4 + i;
      linv[i] = 1.0f / (Ls[ql] + Ls[32 + ql] + Ls[64 + ql] + Ls[96 + ql]);
    }
    #pragma unroll
    for (int ch = 0; ch < 4; ++ch) {
      int d = w * 64 + ch * 16 + lr;
      #pragma unroll
      for (int i = 0; i < 4; ++i) {
        int q = q0 + qt * 16 + g * 4 + i;
        Out[((size_t)q * NB + b) * DD + d] = acc[qt][ch][i] * linv[i];
      }
    }
  }
}

// ==========================================================================
extern "C" void kernel_launch(void* const* d_in, const int* in_sizes, int n_in,
                              void* d_out, int out_size, void* d_ws, size_t ws_size,
                              hipStream_t stream) {
  const float* query = (const float*)d_in[0];
  const float* key   = (const float*)d_in[1];
  const float* value = (const float*)d_in[2];
  const float* WKw   = (const float*)d_in[3];
  const float* WKb   = (const float*)d_in[4];
  const float* WVw   = (const float*)d_in[5];
  const float* WVb   = (const float*)d_in[6];
  float* out = (float*)d_out;

  unsigned short* wqn = (unsigned short*)d_ws;            // [4][4096][128] bf16
  unsigned short* wkn = wqn + (size_t)NB * LL * KDIM;     // [4][4096][128] bf16
  unsigned short* vt  = wkn + (size_t)NB * LL * KDIM;     // [4][512][4096] bf16

  proj_qk_kernel<<<512, 256, 0, stream>>>(query, key, WKw, WKb, wqn, wkn);
  proj_v_kernel <<<512, 256, 0, stream>>>(value, WVw, WVb, vt);
  attn_kernel   <<<512, 512, 0, stream>>>(wqn, wkn, vt, out);
}

// Round 10
// 313.154 us; speedup vs baseline: 1.7122x; 1.1973x over previous
//
#include <hip/hip_runtime.h>

// ---------- types ----------
using bf16x8 = __attribute__((ext_vector_type(8))) short;           // 8 bf16 (4 VGPR)
using u16x8  = __attribute__((ext_vector_type(8))) unsigned short;  // 16B staging
using f32x4  = __attribute__((ext_vector_type(4))) float;
using f32x4v = __attribute__((ext_vector_type(4))) float;

__device__ inline unsigned short f2bf(float f) {
  unsigned int u = __builtin_bit_cast(unsigned int, f);
  return (unsigned short)((u + 0x7fffu + ((u >> 16) & 1u)) >> 16);  // RNE
}

#define MFMA16(a, b, c) __builtin_amdgcn_mfma_f32_16x16x32_bf16((a), (b), (c), 0, 0, 0)

// LDS-visibility-only barrier: drains lgkmcnt but NOT vmcnt, so register-
// destined global prefetches stay in flight across the sync (v3-proven).
__device__ __forceinline__ void lds_barrier() {
  __builtin_amdgcn_sched_barrier(0);
  asm volatile("s_waitcnt lgkmcnt(0)" ::: "memory");
  __builtin_amdgcn_sched_barrier(0);
  __builtin_amdgcn_s_barrier();
  __builtin_amdgcn_sched_barrier(0);
}

// Problem constants
#define LL 4096
#define NB 4
#define DD 512
#define KDIM 128

// ==========================================================================
// proj_qk (merged q+k): Out[b][l][128] = bf16( l2norm( X[l][b][:] @ Wk^T + bk ) )
// ==========================================================================
__global__ __launch_bounds__(256) void proj_qk_kernel(
    const float* __restrict__ Xq, const float* __restrict__ Xk,
    const float* __restrict__ Wk, const float* __restrict__ bk,
    unsigned short* __restrict__ Outq, unsigned short* __restrict__ Outk)
{
  __shared__ char smem[49152];                       // Xs 16KB | Ws 32KB
  char* Xs = smem;
  char* Ws = smem + 16384;

  const int tid = threadIdx.x;
  const int w = tid >> 6, lane = tid & 63, lr = lane & 15, g = lane >> 4;
  const int sel = blockIdx.x & 1;
  const float* X = sel ? Xk : Xq;
  unsigned short* Out = sel ? Outk : Outq;
  const int r0 = (blockIdx.x >> 1) * 64;

  f32x4 acc[8];
  #pragma unroll
  for (int nt = 0; nt < 8; ++nt) acc[nt] = f32x4{0.f, 0.f, 0.f, 0.f};

  for (int kc = 0; kc < 4; ++kc) {                   // K chunks of 128
    if (kc) __syncthreads();
    #pragma unroll
    for (int p = 0; p < 4; ++p) {
      int j = tid + p * 256;
      int row = j >> 4, e0 = (j & 15) * 8;
      const float* src = X + (size_t)(r0 + row) * DD + kc * 128 + e0;
      f32x4v f0 = *reinterpret_cast<const f32x4v*>(src);
      f32x4v f1 = *reinterpret_cast<const f32x4v*>(src + 4);
      u16x8 v;
      #pragma unroll
      for (int e = 0; e < 4; ++e) { v[e] = f2bf(f0[e]); v[e + 4] = f2bf(f1[e]); }
      *reinterpret_cast<u16x8*>(Xs + row * 256 + ((e0 * 2) ^ ((row & 7) << 4))) = v;
    }
    #pragma unroll
    for (int p = 0; p < 8; ++p) {
      int j = tid + p * 256;
      int n = j >> 4, e0 = (j & 15) * 8;
      const float* src = Wk + (size_t)n * DD + kc * 128 + e0;
      f32x4v f0 = *reinterpret_cast<const f32x4v*>(src);
      f32x4v f1 = *reinterpret_cast<const f32x4v*>(src + 4);
      u16x8 v;
      #pragma unroll
      for (int e = 0; e < 4; ++e) { v[e] = f2bf(f0[e]); v[e + 4] = f2bf(f1[e]); }
      *reinterpret_cast<u16x8*>(Ws + n * 256 + ((e0 * 2) ^ ((n & 7) << 4))) = v;
    }
    __syncthreads();
    const int arow = w * 16 + lr;
    #pragma unroll
    for (int ks = 0; ks < 4; ++ks) {
      int oa = (ks * 64 + g * 16) ^ ((arow & 7) << 4);
      bf16x8 a = *reinterpret_cast<const bf16x8*>(Xs + arow * 256 + oa);
      #pragma unroll
      for (int nt = 0; nt < 8; ++nt) {
        int n = nt * 16 + lr;
        int ob = (ks * 64 + g * 16) ^ ((n & 7) << 4);
        bf16x8 bb = *reinterpret_cast<const bf16x8*>(Ws + n * 256 + ob);
        acc[nt] = MFMA16(a, bb, acc[nt]);
      }
    }
  }

  float bias[8];
  #pragma unroll
  for (int nt = 0; nt < 8; ++nt) bias[nt] = bk[nt * 16 + lr];
  #pragma unroll
  for (int nt = 0; nt < 8; ++nt)
    #pragma unroll
    for (int i = 0; i < 4; ++i) acc[nt][i] += bias[nt];

  f32x4 ss = f32x4{0.f, 0.f, 0.f, 0.f};
  #pragma unroll
  for (int nt = 0; nt < 8; ++nt)
    #pragma unroll
    for (int i = 0; i < 4; ++i) ss[i] += acc[nt][i] * acc[nt][i];
  #pragma unroll
  for (int m = 1; m < 16; m <<= 1) {
    #pragma unroll
    for (int i = 0; i < 4; ++i) ss[i] += __shfl_xor(ss[i], m);
  }
  float inv[4];
  #pragma unroll
  for (int i = 0; i < 4; ++i) inv[i] = 1.0f / fmaxf(sqrtf(ss[i]), 1e-12f);

  #pragma unroll
  for (int nt = 0; nt < 8; ++nt) {
    int c = nt * 16 + lr;
    #pragma unroll
    for (int i = 0; i < 4; ++i) {
      int r = r0 + w * 16 + g * 4 + i;
      int l = r >> 2, b = r & 3;
      Out[((size_t)(b * LL + l)) * KDIM + c] = f2bf(acc[nt][i] * inv[i]);
    }
  }
}

// ==========================================================================
// proj_v: Vt[b][d][s] = bf16( value[s][b][:] @ Wv^T + bv )   (transposed store)
// ==========================================================================
__global__ __launch_bounds__(256) void proj_v_kernel(
    const float* __restrict__ X, const float* __restrict__ Wv,
    const float* __restrict__ bv, unsigned short* __restrict__ VtOut)
{
  __shared__ char smem[40960];
  char* Xs = smem;
  char* Ws = smem + 32768;

  const int tid = threadIdx.x;
  const int w = tid >> 6, lane = tid & 63, lr = lane & 15, g = lane >> 4;
  const int rb = blockIdx.x >> 3, nb = blockIdx.x & 7;
  const int r0 = rb * 256, d0 = nb * 64;

  f32x4 acc[4][4];
  #pragma unroll
  for (int rt = 0; rt < 4; ++rt)
    #pragma unroll
    for (int nt = 0; nt < 4; ++nt) acc[rt][nt] = f32x4{0.f, 0.f, 0.f, 0.f};

  for (int kc = 0; kc < 8; ++kc) {
    if (kc) __syncthreads();
    #pragma unroll
    for (int p = 0; p < 8; ++p) {
      int j = tid + p * 256;
      int row = j >> 3, e0 = (j & 7) * 8;
      const float* src = X + (size_t)(r0 + row) * DD + kc * 64 + e0;
      f32x4v f0 = *reinterpret_cast<const f32x4v*>(src);
      f32x4v f1 = *reinterpret_cast<const f32x4v*>(src + 4);
      u16x8 v;
      #pragma unroll
      for (int e = 0; e < 4; ++e) { v[e] = f2bf(f0[e]); v[e + 4] = f2bf(f1[e]); }
      *reinterpret_cast<u16x8*>(Xs + row * 128 + ((e0 * 2) ^ ((row & 7) << 4))) = v;
    }
    #pragma unroll
    for (int p = 0; p < 2; ++p) {
      int j = tid + p * 256;
      int n = j >> 3, e0 = (j & 7) * 8;
      const float* src = Wv + (size_t)(d0 + n) * DD + kc * 64 + e0;
      f32x4v f0 = *reinterpret_cast<const f32x4v*>(src);
      f32x4v f1 = *reinterpret_cast<const f32x4v*>(src + 4);
      u16x8 v;
      #pragma unroll
      for (int e = 0; e < 4; ++e) { v[e] = f2bf(f0[e]); v[e + 4] = f2bf(f1[e]); }
      *reinterpret_cast<u16x8*>(Ws + n * 128 + ((e0 * 2) ^ ((n & 7) << 4))) = v;
    }
    __syncthreads();
    #pragma unroll
    for (int ks = 0; ks < 2; ++ks) {
      bf16x8 a[4];
      #pragma unroll
      for (int rt = 0; rt < 4; ++rt) {
        int arow = w * 64 + rt * 16 + lr;
        a[rt] = *reinterpret_cast<const bf16x8*>(
            Xs + arow * 128 + ((ks * 64 + g * 16) ^ ((arow & 7) << 4)));
      }
      #pragma unroll
      for (int nt = 0; nt < 4; ++nt) {
        int n = nt * 16 + lr;
        bf16x8 bb = *reinterpret_cast<const bf16x8*>(
            Ws + n * 128 + ((ks * 64 + g * 16) ^ ((n & 7) << 4)));
        #pragma unroll
        for (int rt = 0; rt < 4; ++rt) acc[rt][nt] = MFMA16(a[rt], bb, acc[rt][nt]);
      }
    }
  }

  __syncthreads();
  float bias[4];
  #pragma unroll
  for (int nt = 0; nt < 4; ++nt) bias[nt] = bv[d0 + nt * 16 + lr];

  unsigned short* Ts = (unsigned short*)smem;
  #pragma unroll
  for (int rt = 0; rt < 4; ++rt)
    #pragma unroll
    for (int nt = 0; nt < 4; ++nt) {
      int dl = nt * 16 + lr;
      #pragma unroll
      for (int i = 0; i < 4; ++i) {
        int rl = w * 64 + rt * 16 + g * 4 + i;
        Ts[dl * 256 + (rl ^ ((dl & 31) << 1))] = f2bf(acc[rt][nt][i] + bias[nt]);
      }
    }
  __syncthreads();

  int bsel = tid >> 6, dl = tid & 63;
  int l0 = r0 >> 2;
  #pragma unroll
  for (int jj = 0; jj < 8; ++jj) {
    u16x8 v;
    #pragma unroll
    for (int e = 0; e < 8; ++e) {
      int rl = (jj * 8 + e) * 4 + bsel;
      v[e] = Ts[dl * 256 + (rl ^ ((dl & 31) << 1))];
    }
    *reinterpret_cast<u16x8*>(VtOut + ((size_t)(bsel * DD + d0 + dl)) * LL + l0 + jj * 8) = v;
  }
}

// ==========================================================================
// attn v10: v3 tiling (QBLK=64, KBLK=64, grid 256, 8 waves, 2/SIMD) but with
// K held ONLY in registers (single-buffered consume-then-refill, like V):
//  - no K LDS tile, no K staging -> LDS = P dbuf only (16.9 KB)
//  - 4 waves per s-half read identical K lines -> L1-served after first wave
// Step: [pf ds_reads -> lgkm wait -> 40-MFMA burst (S from kb + PV(t-1)) ->
//        refill kb<-K(t+1), vst<-V(t) -> exp + P(t) write -> lgkm-only barrier]
// ==========================================================================
#define QBLK 64
#define KBLK 64
#define NIT (LL / KBLK)          // 64 steps

template<bool DOPV>
__device__ __forceinline__ void attn_step10(
    int t, const unsigned short* __restrict__ Kp,
    const unsigned short* __restrict__ Vp,
    const char* prd, char* pwr,
    const bf16x8 (&qf)[4], bf16x8 (&kb)[2][4], bf16x8 (&vst)[4][2],
    f32x4 (&acc)[4][4], float (&lsum)[4],
    int lr, int g, int w, int wq, int ws)
{
  // ---- 1. P(t-1) fragment ds_reads ----
  bf16x8 pf[4][2];
  if (DOPV) {
    #pragma unroll
    for (int qt = 0; qt < 4; ++qt) {
      int q = qt * 16 + lr, sw = (q & 7) << 4;
      pf[qt][0] = *reinterpret_cast<const bf16x8*>(prd + q * 128 + ((g * 16) ^ sw));
      pf[qt][1] = *reinterpret_cast<const bf16x8*>(prd + q * 128 + ((64 + g * 16) ^ sw));
    }
    __builtin_amdgcn_sched_barrier(0);
    asm volatile("s_waitcnt lgkmcnt(0)" ::: "memory");
    __builtin_amdgcn_sched_barrier(0);
  }

  // ---- 2. MFMA burst: S(t) from kb regs, then PV(t-1) ----
  f32x4 s0 = f32x4{0.f, 0.f, 0.f, 0.f};
  f32x4 s1 = f32x4{0.f, 0.f, 0.f, 0.f};
  __builtin_amdgcn_s_setprio(1);
  #pragma unroll
  for (int kc = 0; kc < 4; ++kc) {
    s0 = MFMA16(qf[kc], kb[0][kc], s0);
    s1 = MFMA16(qf[kc], kb[1][kc], s1);
  }
  if (DOPV) {
    #pragma unroll
    for (int qt = 0; qt < 4; ++qt)
      #pragma unroll
      for (int ch = 0; ch < 4; ++ch) {
        acc[qt][ch] = MFMA16(pf[qt][0], vst[ch][0], acc[qt][ch]);
        acc[qt][ch] = MFMA16(pf[qt][1], vst[ch][1], acc[qt][ch]);
      }
  }
  __builtin_amdgcn_s_setprio(0);

  // ---- 3. refill kb <- K(t+1), vst <- V(t) (regs just consumed; loads
  //         stay in flight across the barrier, used next step) ----
  const int tn = (t + 1 < NIT) ? t + 1 : NIT - 1;
  #pragma unroll
  for (int sch = 0; sch < 2; ++sch) {
    int sr = ws * 32 + sch * 16 + lr;
    #pragma unroll
    for (int kc = 0; kc < 4; ++kc)
      kb[sch][kc] = *reinterpret_cast<const bf16x8*>(
          Kp + ((size_t)(tn * KBLK + sr)) * KDIM + kc * 32 + g * 8);
  }
  #pragma unroll
  for (int ch = 0; ch < 4; ++ch)
    #pragma unroll
    for (int sc = 0; sc < 2; ++sc)
      vst[ch][sc] = *reinterpret_cast<const bf16x8*>(
          Vp + (size_t)(w * 64 + ch * 16 + lr) * LL + t * KBLK + sc * 32 + g * 8);

  // ---- 4. softmax numerator (fixed max 31) + P(t) write ----
  const int sr0 = ws * 32 + lr, sr1 = sr0 + 16;
  #pragma unroll
  for (int i = 0; i < 4; ++i) {
    float p0 = exp2f(fmaf(s0[i], 43.280851f, -44.723546f));
    float p1 = exp2f(fmaf(s1[i], 43.280851f, -44.723546f));
    lsum[i] += p0 + p1;
    int q = wq * 16 + g * 4 + i, sw = (q & 7) << 4;
    *(unsigned short*)(pwr + q * 128 + ((sr0 * 2) ^ sw)) = f2bf(p0);
    *(unsigned short*)(pwr + q * 128 + ((sr1 * 2) ^ sw)) = f2bf(p1);
  }

  lds_barrier();   // lgkm-only: K/V global refills stay in flight
}

__global__ __launch_bounds__(512, 2) void attn_kernel(
    const unsigned short* __restrict__ Qn, const unsigned short* __restrict__ Kn,
    const unsigned short* __restrict__ Vt, float* __restrict__ Out)
{
  __shared__ char smem[16896];
  char* Ps0 = smem;                                  // [64 q][64 s] bf16, 8KB
  char* Ps1 = smem + 8192;
  float* Ls = (float*)(smem + 16384);                // [2][64] partial row sums

  const int tid = threadIdx.x;
  const int w = tid >> 6, lane = tid & 63, lr = lane & 15, g = lane >> 4;
  const int wq = w & 3, ws = w >> 2;

  // XCD-grouping swizzle: batch b -> XCD pair {2b,2b+1} (rr dispatch)
  const int bid = blockIdx.x;
  const int b = (bid & 7) >> 1;
  const int tile = ((bid >> 3) << 1) | (bid & 1);
  const int q0 = tile * QBLK;

  const unsigned short* Kp = Kn + (size_t)b * LL * KDIM;
  const unsigned short* Vp = Vt + (size_t)b * DD * LL;

  // Q A-fragments (KD=128 -> 4 chunks of 32)
  bf16x8 qf[4];
  {
    const unsigned short* qp = Qn + ((size_t)(b * LL + q0 + wq * 16 + lr)) * KDIM + g * 8;
    #pragma unroll
    for (int kc = 0; kc < 4; ++kc)
      qf[kc] = *reinterpret_cast<const bf16x8*>(qp + kc * 32);
  }

  f32x4 acc[4][4];
  #pragma unroll
  for (int qt = 0; qt < 4; ++qt)
    #pragma unroll
    for (int ch = 0; ch < 4; ++ch) acc[qt][ch] = f32x4{0.f, 0.f, 0.f, 0.f};
  float lsum[4] = {0.f, 0.f, 0.f, 0.f};

  bf16x8 kb[2][4];        // K(t) fragments, 32 VGPR
  bf16x8 vst[4][2];       // V(t-1) fragments, 32 VGPR

  // ---- prologue: kb <- K(0) ----
  #pragma unroll
  for (int sch = 0; sch < 2; ++sch) {
    int sr = ws * 32 + sch * 16 + lr;
    #pragma unroll
    for (int kc = 0; kc < 4; ++kc)
      kb[sch][kc] = *reinterpret_cast<const bf16x8*>(
          Kp + (size_t)sr * KDIM + kc * 32 + g * 8);
  }
  __syncthreads();

  // ---- t=0: S only (also loads V(0)->vst, K(1)->kb) ----
  attn_step10<false>(0, Kp, Vp, Ps1, Ps0, qf, kb, vst, acc, lsum, lr, g, w, wq, ws);

  // ---- main loop: t=1..62 in pairs (static buffer naming) ----
  for (int t = 1; t < 63; t += 2) {
    attn_step10<true>(t,     Kp, Vp, Ps0, Ps1, qf, kb, vst, acc, lsum, lr, g, w, wq, ws);
    attn_step10<true>(t + 1, Kp, Vp, Ps1, Ps0, qf, kb, vst, acc, lsum, lr, g, w, wq, ws);
  }
  // ---- t=63 ----
  attn_step10<true>(63, Kp, Vp, Ps0, Ps1, qf, kb, vst, acc, lsum, lr, g, w, wq, ws);

  // ---- epilogue PV(63): P from Ps1, V(63) in vst ----
  #pragma unroll
  for (int qt = 0; qt < 4; ++qt) {
    int q = qt * 16 + lr, sw = (q & 7) << 4;
    bf16x8 pa0 = *reinterpret_cast<const bf16x8*>(Ps1 + q * 128 + ((g * 16) ^ sw));
    bf16x8 pa1 = *reinterpret_cast<const bf16x8*>(Ps1 + q * 128 + ((64 + g * 16) ^ sw));
    #pragma unroll
    for (int ch = 0; ch < 4; ++ch) {
      acc[qt][ch] = MFMA16(pa0, vst[ch][0], acc[qt][ch]);
      acc[qt][ch] = MFMA16(pa1, vst[ch][1], acc[qt][ch]);
    }
  }

  // ---- combine partial row sums across the two s-halves ----
  #pragma unroll
  for (int m = 1; m < 16; m <<= 1) {
    #pragma unroll
    for (int i = 0; i < 4; ++i) lsum[i] += __shfl_xor(lsum[i], m);
  }
  if (lr == 0) {
    #pragma unroll
    for (int i = 0; i < 4; ++i) Ls[ws * 64 + wq * 16 + g * 4 + i] = lsum[i];
  }
  __syncthreads();

  // ---- scale by 1/l and store ----
  #pragma unroll
  for (int qt = 0; qt < 4; ++qt) {
    float linv[4];
    #pragma unroll
    for (int i = 0; i < 4; ++i) {
      int q = qt * 16 + g * 4 + i;
      linv[i] = 1.0f / (Ls[q] + Ls[64 + q]);
    }
    #pragma unroll
    for (int ch = 0; ch < 4; ++ch) {
      int d = w * 64 + ch * 16 + lr;
      #pragma unroll
      for (int i = 0; i < 4; ++i) {
        int q = q0 + qt * 16 + g * 4 + i;
        Out[((size_t)q * NB + b) * DD + d] = acc[qt][ch][i] * linv[i];
      }
    }
  }
}

// ==========================================================================
extern "C" void kernel_launch(void* const* d_in, const int* in_sizes, int n_in,
                              void* d_out, int out_size, void* d_ws, size_t ws_size,
                              hipStream_t stream) {
  const float* query = (const float*)d_in[0];
  const float* key   = (const float*)d_in[1];
  const float* value = (const float*)d_in[2];
  const float* WKw   = (const float*)d_in[3];
  const float* WKb   = (const float*)d_in[4];
  const float* WVw   = (const float*)d_in[5];
  const float* WVb   = (const float*)d_in[6];
  float* out = (float*)d_out;

  unsigned short* wqn = (unsigned short*)d_ws;            // [4][4096][128] bf16
  unsigned short* wkn = wqn + (size_t)NB * LL * KDIM;     // [4][4096][128] bf16
  unsigned short* vt  = wkn + (size_t)NB * LL * KDIM;     // [4][512][4096] bf16

  proj_qk_kernel<<<512, 256, 0, stream>>>(query, key, WKw, WKb, wqn, wkn);
  proj_v_kernel <<<512, 256, 0, stream>>>(value, WVw, WVb, vt);
  attn_kernel   <<<256, 512, 0, stream>>>(wqn, wkn, vt, out);
}

// Round 11
// 298.245 us; speedup vs baseline: 1.7977x; 1.0500x over previous
//
#include <hip/hip_runtime.h>

// ---------- types ----------
using bf16x8 = __attribute__((ext_vector_type(8))) short;           // 8 bf16 (4 VGPR)
using u16x8  = __attribute__((ext_vector_type(8))) unsigned short;  // 16B staging
using f32x4  = __attribute__((ext_vector_type(4))) float;
using f32x4v = __attribute__((ext_vector_type(4))) float;

__device__ inline unsigned short f2bf(float f) {
  unsigned int u = __builtin_bit_cast(unsigned int, f);
  return (unsigned short)((u + 0x7fffu + ((u >> 16) & 1u)) >> 16);  // RNE
}

#define MFMA16(a, b, c) __builtin_amdgcn_mfma_f32_16x16x32_bf16((a), (b), (c), 0, 0, 0)

// LDS-visibility-only barrier: drains lgkmcnt but NOT vmcnt, so register-
// destined global prefetches stay in flight across the sync (v3-proven).
__device__ __forceinline__ void lds_barrier() {
  __builtin_amdgcn_sched_barrier(0);
  asm volatile("s_waitcnt lgkmcnt(0)" ::: "memory");
  __builtin_amdgcn_sched_barrier(0);
  __builtin_amdgcn_s_barrier();
  __builtin_amdgcn_sched_barrier(0);
}

// Problem constants
#define LL 4096
#define NB 4
#define DD 512
#define KDIM 128

// ==========================================================================
// proj_qk (merged q+k): Out[b][l][128] = bf16( l2norm( X[l][b][:] @ Wk^T + bk ) )
// ==========================================================================
__global__ __launch_bounds__(256) void proj_qk_kernel(
    const float* __restrict__ Xq, const float* __restrict__ Xk,
    const float* __restrict__ Wk, const float* __restrict__ bk,
    unsigned short* __restrict__ Outq, unsigned short* __restrict__ Outk)
{
  __shared__ char smem[49152];                       // Xs 16KB | Ws 32KB
  char* Xs = smem;
  char* Ws = smem + 16384;

  const int tid = threadIdx.x;
  const int w = tid >> 6, lane = tid & 63, lr = lane & 15, g = lane >> 4;
  const int sel = blockIdx.x & 1;
  const float* X = sel ? Xk : Xq;
  unsigned short* Out = sel ? Outk : Outq;
  const int r0 = (blockIdx.x >> 1) * 64;

  f32x4 acc[8];
  #pragma unroll
  for (int nt = 0; nt < 8; ++nt) acc[nt] = f32x4{0.f, 0.f, 0.f, 0.f};

  for (int kc = 0; kc < 4; ++kc) {                   // K chunks of 128
    if (kc) __syncthreads();
    #pragma unroll
    for (int p = 0; p < 4; ++p) {
      int j = tid + p * 256;
      int row = j >> 4, e0 = (j & 15) * 8;
      const float* src = X + (size_t)(r0 + row) * DD + kc * 128 + e0;
      f32x4v f0 = *reinterpret_cast<const f32x4v*>(src);
      f32x4v f1 = *reinterpret_cast<const f32x4v*>(src + 4);
      u16x8 v;
      #pragma unroll
      for (int e = 0; e < 4; ++e) { v[e] = f2bf(f0[e]); v[e + 4] = f2bf(f1[e]); }
      *reinterpret_cast<u16x8*>(Xs + row * 256 + ((e0 * 2) ^ ((row & 7) << 4))) = v;
    }
    #pragma unroll
    for (int p = 0; p < 8; ++p) {
      int j = tid + p * 256;
      int n = j >> 4, e0 = (j & 15) * 8;
      const float* src = Wk + (size_t)n * DD + kc * 128 + e0;
      f32x4v f0 = *reinterpret_cast<const f32x4v*>(src);
      f32x4v f1 = *reinterpret_cast<const f32x4v*>(src + 4);
      u16x8 v;
      #pragma unroll
      for (int e = 0; e < 4; ++e) { v[e] = f2bf(f0[e]); v[e + 4] = f2bf(f1[e]); }
      *reinterpret_cast<u16x8*>(Ws + n * 256 + ((e0 * 2) ^ ((n & 7) << 4))) = v;
    }
    __syncthreads();
    const int arow = w * 16 + lr;
    #pragma unroll
    for (int ks = 0; ks < 4; ++ks) {
      int oa = (ks * 64 + g * 16) ^ ((arow & 7) << 4);
      bf16x8 a = *reinterpret_cast<const bf16x8*>(Xs + arow * 256 + oa);
      #pragma unroll
      for (int nt = 0; nt < 8; ++nt) {
        int n = nt * 16 + lr;
        int ob = (ks * 64 + g * 16) ^ ((n & 7) << 4);
        bf16x8 bb = *reinterpret_cast<const bf16x8*>(Ws + n * 256 + ob);
        acc[nt] = MFMA16(a, bb, acc[nt]);
      }
    }
  }

  float bias[8];
  #pragma unroll
  for (int nt = 0; nt < 8; ++nt) bias[nt] = bk[nt * 16 + lr];
  #pragma unroll
  for (int nt = 0; nt < 8; ++nt)
    #pragma unroll
    for (int i = 0; i < 4; ++i) acc[nt][i] += bias[nt];

  f32x4 ss = f32x4{0.f, 0.f, 0.f, 0.f};
  #pragma unroll
  for (int nt = 0; nt < 8; ++nt)
    #pragma unroll
    for (int i = 0; i < 4; ++i) ss[i] += acc[nt][i] * acc[nt][i];
  #pragma unroll
  for (int m = 1; m < 16; m <<= 1) {
    #pragma unroll
    for (int i = 0; i < 4; ++i) ss[i] += __shfl_xor(ss[i], m);
  }
  float inv[4];
  #pragma unroll
  for (int i = 0; i < 4; ++i) inv[i] = 1.0f / fmaxf(sqrtf(ss[i]), 1e-12f);

  #pragma unroll
  for (int nt = 0; nt < 8; ++nt) {
    int c = nt * 16 + lr;
    #pragma unroll
    for (int i = 0; i < 4; ++i) {
      int r = r0 + w * 16 + g * 4 + i;
      int l = r >> 2, b = r & 3;
      Out[((size_t)(b * LL + l)) * KDIM + c] = f2bf(acc[nt][i] * inv[i]);
    }
  }
}

// ==========================================================================
// proj_v: Vt[b][d][s] = bf16( value[s][b][:] @ Wv^T + bv )   (transposed store)
// ==========================================================================
__global__ __launch_bounds__(256) void proj_v_kernel(
    const float* __restrict__ X, const float* __restrict__ Wv,
    const float* __restrict__ bv, unsigned short* __restrict__ VtOut)
{
  __shared__ char smem[40960];
  char* Xs = smem;
  char* Ws = smem + 32768;

  const int tid = threadIdx.x;
  const int w = tid >> 6, lane = tid & 63, lr = lane & 15, g = lane >> 4;
  const int rb = blockIdx.x >> 3, nb = blockIdx.x & 7;
  const int r0 = rb * 256, d0 = nb * 64;

  f32x4 acc[4][4];
  #pragma unroll
  for (int rt = 0; rt < 4; ++rt)
    #pragma unroll
    for (int nt = 0; nt < 4; ++nt) acc[rt][nt] = f32x4{0.f, 0.f, 0.f, 0.f};

  for (int kc = 0; kc < 8; ++kc) {
    if (kc) __syncthreads();
    #pragma unroll
    for (int p = 0; p < 8; ++p) {
      int j = tid + p * 256;
      int row = j >> 3, e0 = (j & 7) * 8;
      const float* src = X + (size_t)(r0 + row) * DD + kc * 64 + e0;
      f32x4v f0 = *reinterpret_cast<const f32x4v*>(src);
      f32x4v f1 = *reinterpret_cast<const f32x4v*>(src + 4);
      u16x8 v;
      #pragma unroll
      for (int e = 0; e < 4; ++e) { v[e] = f2bf(f0[e]); v[e + 4] = f2bf(f1[e]); }
      *reinterpret_cast<u16x8*>(Xs + row * 128 + ((e0 * 2) ^ ((row & 7) << 4))) = v;
    }
    #pragma unroll
    for (int p = 0; p < 2; ++p) {
      int j = tid + p * 256;
      int n = j >> 3, e0 = (j & 7) * 8;
      const float* src = Wv + (size_t)(d0 + n) * DD + kc * 64 + e0;
      f32x4v f0 = *reinterpret_cast<const f32x4v*>(src);
      f32x4v f1 = *reinterpret_cast<const f32x4v*>(src + 4);
      u16x8 v;
      #pragma unroll
      for (int e = 0; e < 4; ++e) { v[e] = f2bf(f0[e]); v[e + 4] = f2bf(f1[e]); }
      *reinterpret_cast<u16x8*>(Ws + n * 128 + ((e0 * 2) ^ ((n & 7) << 4))) = v;
    }
    __syncthreads();
    #pragma unroll
    for (int ks = 0; ks < 2; ++ks) {
      bf16x8 a[4];
      #pragma unroll
      for (int rt = 0; rt < 4; ++rt) {
        int arow = w * 64 + rt * 16 + lr;
        a[rt] = *reinterpret_cast<const bf16x8*>(
            Xs + arow * 128 + ((ks * 64 + g * 16) ^ ((arow & 7) << 4)));
      }
      #pragma unroll
      for (int nt = 0; nt < 4; ++nt) {
        int n = nt * 16 + lr;
        bf16x8 bb = *reinterpret_cast<const bf16x8*>(
            Ws + n * 128 + ((ks * 64 + g * 16) ^ ((n & 7) << 4)));
        #pragma unroll
        for (int rt = 0; rt < 4; ++rt) acc[rt][nt] = MFMA16(a[rt], bb, acc[rt][nt]);
      }
    }
  }

  __syncthreads();
  float bias[4];
  #pragma unroll
  for (int nt = 0; nt < 4; ++nt) bias[nt] = bv[d0 + nt * 16 + lr];

  unsigned short* Ts = (unsigned short*)smem;
  #pragma unroll
  for (int rt = 0; rt < 4; ++rt)
    #pragma unroll
    for (int nt = 0; nt < 4; ++nt) {
      int dl = nt * 16 + lr;
      #pragma unroll
      for (int i = 0; i < 4; ++i) {
        int rl = w * 64 + rt * 16 + g * 4 + i;
        Ts[dl * 256 + (rl ^ ((dl & 31) << 1))] = f2bf(acc[rt][nt][i] + bias[nt]);
      }
    }
  __syncthreads();

  int bsel = tid >> 6, dl = tid & 63;
  int l0 = r0 >> 2;
  #pragma unroll
  for (int jj = 0; jj < 8; ++jj) {
    u16x8 v;
    #pragma unroll
    for (int e = 0; e < 8; ++e) {
      int rl = (jj * 8 + e) * 4 + bsel;
      v[e] = Ts[dl * 256 + (rl ^ ((dl & 31) << 1))];
    }
    *reinterpret_cast<u16x8*>(VtOut + ((size_t)(bsel * DD + d0 + dl)) * LL + l0 + jj * 8) = v;
  }
}

// ==========================================================================
// attn v11: v3 dataflow + WAVE-PARITY PHASE STAGGER.
// Both S(t) and PV(t-1) are data-ready at step start, so:
//   even waves run [S -> PV], odd waves run [PV -> S].
// At any instant one wave of each SIMD pair is in an LDS-read phase while
// the other is in an MFMA burst -> the pipes overlap instead of convoying.
// Everything else identical to v3/v7 (proven): K dbuf + P dbuf in LDS,
// V consume-then-refill regs, lgkm-only barrier, XCD swizzle.
// ==========================================================================
#define QBLK 64
#define KBLK 64
#define NIT (LL / KBLK)          // 64 steps

struct ACtx {
  const unsigned short* Kp;
  const unsigned short* Vp;
  int lr, g, w, wq, ws, r0k, c0k;
};

// S phase: K(t) frags from LDS -> 8 MFMA -> exp -> P(t) write.
__device__ __forceinline__ void do_s(
    const ACtx& c, const char* kcur, char* pwr,
    const bf16x8 (&qf)[4], float (&lsum)[4])
{
  bf16x8 kb[2][4];
  #pragma unroll
  for (int sch = 0; sch < 2; ++sch) {
    int sr = c.ws * 32 + sch * 16 + c.lr;
    #pragma unroll
    for (int kc = 0; kc < 4; ++kc)
      kb[sch][kc] = *reinterpret_cast<const bf16x8*>(
          kcur + sr * 256 + ((kc * 64 + c.g * 16) ^ ((sr & 7) << 4)));
  }
  __builtin_amdgcn_sched_barrier(0);
  asm volatile("s_waitcnt lgkmcnt(0)" ::: "memory");
  __builtin_amdgcn_sched_barrier(0);

  f32x4 s0 = f32x4{0.f, 0.f, 0.f, 0.f};
  f32x4 s1 = f32x4{0.f, 0.f, 0.f, 0.f};
  __builtin_amdgcn_s_setprio(1);
  #pragma unroll
  for (int kc = 0; kc < 4; ++kc) {
    s0 = MFMA16(qf[kc], kb[0][kc], s0);
    s1 = MFMA16(qf[kc], kb[1][kc], s1);
  }
  __builtin_amdgcn_s_setprio(0);

  const int sr0 = c.ws * 32 + c.lr, sr1 = sr0 + 16;
  #pragma unroll
  for (int i = 0; i < 4; ++i) {
    float p0 = exp2f(fmaf(s0[i], 43.280851f, -44.723546f));
    float p1 = exp2f(fmaf(s1[i], 43.280851f, -44.723546f));
    lsum[i] += p0 + p1;
    int q = c.wq * 16 + c.g * 4 + i, sw = (q & 7) << 4;
    *(unsigned short*)(pwr + q * 128 + ((sr0 * 2) ^ sw)) = f2bf(p0);
    *(unsigned short*)(pwr + q * 128 + ((sr1 * 2) ^ sw)) = f2bf(p1);
  }
}

// PV phase: P(t-1) frags from LDS x V(t-1) regs -> 32 MFMA -> refill V(t).
__device__ __forceinline__ void do_pv(
    const ACtx& c, int t, const char* prd, bf16x8 (&vst)[4][2],
    f32x4 (&acc)[4][4])
{
  bf16x8 pf[4][2];
  #pragma unroll
  for (int qt = 0; qt < 4; ++qt) {
    int q = qt * 16 + c.lr, sw = (q & 7) << 4;
    pf[qt][0] = *reinterpret_cast<const bf16x8*>(prd + q * 128 + ((c.g * 16) ^ sw));
    pf[qt][1] = *reinterpret_cast<const bf16x8*>(prd + q * 128 + ((64 + c.g * 16) ^ sw));
  }
  __builtin_amdgcn_sched_barrier(0);
  asm volatile("s_waitcnt lgkmcnt(0)" ::: "memory");
  __builtin_amdgcn_sched_barrier(0);

  __builtin_amdgcn_s_setprio(1);
  #pragma unroll
  for (int qt = 0; qt < 4; ++qt)
    #pragma unroll
    for (int ch = 0; ch < 4; ++ch) {
      acc[qt][ch] = MFMA16(pf[qt][0], vst[ch][0], acc[qt][ch]);
      acc[qt][ch] = MFMA16(pf[qt][1], vst[ch][1], acc[qt][ch]);
    }
  __builtin_amdgcn_s_setprio(0);

  // refill vst <- V(t) (regs just consumed; loads span the barrier)
  #pragma unroll
  for (int ch = 0; ch < 4; ++ch)
    #pragma unroll
    for (int sc = 0; sc < 2; ++sc)
      vst[ch][sc] = *reinterpret_cast<const bf16x8*>(
          c.Vp + (size_t)(c.w * 64 + ch * 16 + c.lr) * LL + t * KBLK + sc * 32 + c.g * 8);
}

template<bool DOPV, bool TAIL>
__device__ __forceinline__ void attn_step11(
    const ACtx& c, int t, const char* kcur, char* knxt,
    const char* prd, char* pwr,
    const bf16x8 (&qf)[4], bf16x8 (&vst)[4][2],
    f32x4 (&acc)[4][4], float (&lsum)[4], bool sfirst)
{
  // ---- issue K(t+1) -> regs (oldest vmcnt; full-step cover) ----
  const int tn = TAIL ? t : t + 1;
  u16x8 k0 = *reinterpret_cast<const u16x8*>(
      c.Kp + ((size_t)(tn * KBLK + c.r0k)) * KDIM + c.c0k);
  u16x8 k1 = *reinterpret_cast<const u16x8*>(
      c.Kp + ((size_t)(tn * KBLK + c.r0k + 32)) * KDIM + c.c0k);

  // ---- staggered phases (wave-uniform branch) ----
  if (sfirst) {
    do_s(c, kcur, pwr, qf, lsum);
    if (DOPV) do_pv(c, t, prd, vst, acc);
  } else {
    if (DOPV) do_pv(c, t, prd, vst, acc);
    do_s(c, kcur, pwr, qf, lsum);
  }

  // ---- write staged K(t+1) -> other buffer (counted vmcnt) ----
  {
    int sw = (c.r0k & 7) << 4;
    *reinterpret_cast<u16x8*>(knxt + c.r0k * 256 + ((c.c0k * 2) ^ sw)) = k0;
    *reinterpret_cast<u16x8*>(knxt + (c.r0k + 32) * 256 + ((c.c0k * 2) ^ sw)) = k1;
  }
  lds_barrier();   // lgkm-only: K/V global loads stay in flight
}

__global__ __launch_bounds__(512, 2) void attn_kernel(
    const unsigned short* __restrict__ Qn, const unsigned short* __restrict__ Kn,
    const unsigned short* __restrict__ Vt, float* __restrict__ Out)
{
  __shared__ char smem[49664];
  char* Ks0 = smem;                                  // [64 s][128 k] bf16, 16KB
  char* Ks1 = smem + 16384;
  char* Ps0 = smem + 32768;                          // [64 q][64 s] bf16, 8KB
  char* Ps1 = smem + 40960;
  float* Ls = (float*)(smem + 49152);                // [2][64] partial row sums

  const int tid = threadIdx.x;
  ACtx c;
  c.w = tid >> 6;
  const int lane = tid & 63;
  c.lr = lane & 15; c.g = lane >> 4;
  c.wq = c.w & 3; c.ws = c.w >> 2;
  c.r0k = tid >> 4; c.c0k = (tid & 15) * 8;
  const bool sfirst = (c.w & 1) == 0;

  // XCD-grouping swizzle: batch b -> XCD pair {2b,2b+1} (rr dispatch)
  const int bid = blockIdx.x;
  const int b = (bid & 7) >> 1;
  const int tile = ((bid >> 3) << 1) | (bid & 1);
  const int q0 = tile * QBLK;

  c.Kp = Kn + (size_t)b * LL * KDIM;
  c.Vp = Vt + (size_t)b * DD * LL;

  // Q A-fragments (KD=128 -> 4 chunks of 32)
  bf16x8 qf[4];
  {
    const unsigned short* qp =
        Qn + ((size_t)(b * LL + q0 + c.wq * 16 + c.lr)) * KDIM + c.g * 8;
    #pragma unroll
    for (int kc = 0; kc < 4; ++kc)
      qf[kc] = *reinterpret_cast<const bf16x8*>(qp + kc * 32);
  }

  f32x4 acc[4][4];
  #pragma unroll
  for (int qt = 0; qt < 4; ++qt)
    #pragma unroll
    for (int ch = 0; ch < 4; ++ch) acc[qt][ch] = f32x4{0.f, 0.f, 0.f, 0.f};
  float lsum[4] = {0.f, 0.f, 0.f, 0.f};

  bf16x8 vst[4][2];

  // ---- prologue: K(0) -> Ks0, V(0) -> vst ----
  {
    u16x8 k0 = *reinterpret_cast<const u16x8*>(c.Kp + (size_t)c.r0k * KDIM + c.c0k);
    u16x8 k1 = *reinterpret_cast<const u16x8*>(c.Kp + (size_t)(c.r0k + 32) * KDIM + c.c0k);
    int sw = (c.r0k & 7) << 4;
    *reinterpret_cast<u16x8*>(Ks0 + c.r0k * 256 + ((c.c0k * 2) ^ sw)) = k0;
    *reinterpret_cast<u16x8*>(Ks0 + (c.r0k + 32) * 256 + ((c.c0k * 2) ^ sw)) = k1;
    #pragma unroll
    for (int ch = 0; ch < 4; ++ch)
      #pragma unroll
      for (int sc = 0; sc < 2; ++sc)
        vst[ch][sc] = *reinterpret_cast<const bf16x8*>(
            c.Vp + (size_t)(c.w * 64 + ch * 16 + c.lr) * LL + sc * 32 + c.g * 8);
  }
  __syncthreads();

  // ---- t=0: S only; stages K(1)->Ks1, P(0)->Ps0 ----
  attn_step11<false, false>(c, 0, Ks0, Ks1, Ps1, Ps0, qf, vst, acc, lsum, true);

  // ---- main loop t=1..62 (pairs, static buffer naming) ----
  for (int t = 1; t < 63; t += 2) {
    attn_step11<true, false>(c, t,     Ks1, Ks0, Ps0, Ps1, qf, vst, acc, lsum, sfirst);
    attn_step11<true, false>(c, t + 1, Ks0, Ks1, Ps1, Ps0, qf, vst, acc, lsum, sfirst);
  }
  // ---- t=63 (tail: clamped K prefetch) ----
  attn_step11<true, true>(c, 63, Ks1, Ks0, Ps0, Ps1, qf, vst, acc, lsum, sfirst);

  // ---- epilogue PV(63): P from Ps1, V(63) in vst ----
  #pragma unroll
  for (int qt = 0; qt < 4; ++qt) {
    int q = qt * 16 + c.lr, sw = (q & 7) << 4;
    bf16x8 pa0 = *reinterpret_cast<const bf16x8*>(Ps1 + q * 128 + ((c.g * 16) ^ sw));
    bf16x8 pa1 = *reinterpret_cast<const bf16x8*>(Ps1 + q * 128 + ((64 + c.g * 16) ^ sw));
    #pragma unroll
    for (int ch = 0; ch < 4; ++ch) {
      acc[qt][ch] = MFMA16(pa0, vst[ch][0], acc[qt][ch]);
      acc[qt][ch] = MFMA16(pa1, vst[ch][1], acc[qt][ch]);
    }
  }

  // ---- combine partial row sums across the two s-halves ----
  #pragma unroll
  for (int m = 1; m < 16; m <<= 1) {
    #pragma unroll
    for (int i = 0; i < 4; ++i) lsum[i] += __shfl_xor(lsum[i], m);
  }
  if (c.lr == 0) {
    #pragma unroll
    for (int i = 0; i < 4; ++i) Ls[c.ws * 64 + c.wq * 16 + c.g * 4 + i] = lsum[i];
  }
  __syncthreads();

  // ---- scale by 1/l and store ----
  #pragma unroll
  for (int qt = 0; qt < 4; ++qt) {
    float linv[4];
    #pragma unroll
    for (int i = 0; i < 4; ++i) {
      int q = qt * 16 + c.g * 4 + i;
      linv[i] = 1.0f / (Ls[q] + Ls[64 + q]);
    }
    #pragma unroll
    for (int ch = 0; ch < 4; ++ch) {
      int d = c.w * 64 + ch * 16 + c.lr;
      #pragma unroll
      for (int i = 0; i < 4; ++i) {
        int q = q0 + qt * 16 + c.g * 4 + i;
        Out[((size_t)q * NB + b) * DD + d] = acc[qt][ch][i] * linv[i];
      }
    }
  }
}

// ==========================================================================
extern "C" void kernel_launch(void* const* d_in, const int* in_sizes, int n_in,
                              void* d_out, int out_size, void* d_ws, size_t ws_size,
                              hipStream_t stream) {
  const float* query = (const float*)d_in[0];
  const float* key   = (const float*)d_in[1];
  const float* value = (const float*)d_in[2];
  const float* WKw   = (const float*)d_in[3];
  const float* WKb   = (const float*)d_in[4];
  const float* WVw   = (const float*)d_in[5];
  const float* WVb   = (const float*)d_in[6];
  float* out = (float*)d_out;

  unsigned short* wqn = (unsigned short*)d_ws;            // [4][4096][128] bf16
  unsigned short* wkn = wqn + (size_t)NB * LL * KDIM;     // [4][4096][128] bf16
  unsigned short* vt  = wkn + (size_t)NB * LL * KDIM;     // [4][512][4096] bf16

  proj_qk_kernel<<<512, 256, 0, stream>>>(query, key, WKw, WKb, wqn, wkn);
  proj_v_kernel <<<512, 256, 0, stream>>>(value, WVw, WVb, vt);
  attn_kernel   <<<256, 512, 0, stream>>>(wqn, wkn, vt, out);
}